// Round 10
// baseline (246.109 us; speedup 1.0000x reference)
//
#include <hip/hip_runtime.h>

// AttentionBlock: GN(8 groups) -> 1x1 conv QKV -> attention (B=16,C=512,N=1024) -> 1x1 proj -> +x
// R9: QKV + S on 256x256/BK=64 8-wave 4-phase m201-style schedule: per phase
//     {stage -> ds_read -> BAR -> lgkmcnt(0)+SGB -> setprio MFMA setprio -> BAR}.
//     Race-free by construction: stage into buf[nxt] is >=1 barrier after all waves' reads
//     of it completed; vmcnt(0) at ph3 is two barriers before the next tile's reads.
//     PV/proj on the verified 128^2 2-phase kernel. gn_fused/softmax/f2bf unchanged.

typedef __bf16 bf16x8 __attribute__((ext_vector_type(8)));
typedef float f32x4 __attribute__((ext_vector_type(4)));
typedef unsigned short u16x8 __attribute__((ext_vector_type(8)));
typedef unsigned short u16x4 __attribute__((ext_vector_type(4)));

#define DEVINL __device__ __forceinline__

DEVINL float b2f(unsigned short u) {
  unsigned int x = ((unsigned int)u) << 16;
  return __builtin_bit_cast(float, x);
}
DEVINL unsigned short f2b(float f) {  // RNE f32->bf16
  unsigned int x = __builtin_bit_cast(unsigned int, f);
  x += 0x7fffu + ((x >> 16) & 1u);
  return (unsigned short)(x >> 16);
}

DEVINL void gload16(const void* g, void* l) {
  __builtin_amdgcn_global_load_lds(
      (const __attribute__((address_space(1))) unsigned int*)(const void*)g,
      (__attribute__((address_space(3))) unsigned int*)l, 16, 0, 0);
}

// ---------------- fp32 -> bf16 convert, both weight mats in one dispatch ----------------
__global__ __launch_bounds__(256)
void f2bf_all(const float* __restrict__ qw, const float* __restrict__ pw,
              unsigned short* __restrict__ wq, unsigned short* __restrict__ wp) {
  const int i = blockIdx.x * 256 + threadIdx.x;
  const bool isq = i < 196608;
  const int j = isq ? i : i - 196608;
  float4 v = isq ? ((const float4*)qw)[j] : ((const float4*)pw)[j];
  u16x4 o;
  o[0] = f2b(v.x); o[1] = f2b(v.y); o[2] = f2b(v.z); o[3] = f2b(v.w);
  if (isq) ((u16x4*)wq)[j] = o; else ((u16x4*)wp)[j] = o;
}

// ---------------- fused GroupNorm: stats + apply + transpose ----------------
__global__ __launch_bounds__(512)
void gn_fused(const float* __restrict__ x, const float* __restrict__ gw,
              const float* __restrict__ gb, unsigned short* __restrict__ h) {
  const int b = blockIdx.x >> 3, g = blockIdx.x & 7;
  const float* base = x + (long long)(b * 512 + g * 64) * 1024;
  float s = 0.f, q = 0.f;
  for (int i = threadIdx.x; i < 16384; i += 512) {
    float4 v = ((const float4*)base)[i];
    s += v.x + v.y + v.z + v.w;
    q += v.x * v.x + v.y * v.y + v.z * v.z + v.w * v.w;
  }
#pragma unroll
  for (int off = 32; off; off >>= 1) { s += __shfl_xor(s, off); q += __shfl_xor(q, off); }
  __shared__ float ss[8], qs[8], stats[2];
  const int wave = threadIdx.x >> 6, lane = threadIdx.x & 63;
  if (lane == 0) { ss[wave] = s; qs[wave] = q; }
  __syncthreads();
  if (threadIdx.x == 0) {
    float S = 0.f, Q = 0.f;
#pragma unroll
    for (int w = 0; w < 8; ++w) { S += ss[w]; Q += qs[w]; }
    float mu = S * (1.f / 65536.f);
    float var = Q * (1.f / 65536.f) - mu * mu;
    stats[0] = mu;
    stats[1] = rsqrtf(var + 1e-5f);
  }
  __syncthreads();
  const float mu = stats[0], rs = stats[1];
  __shared__ float t[64][65];
  const int r8 = threadIdx.x >> 6, cl = threadIdx.x & 63;
  for (int pt = 0; pt < 16; ++pt) {
    const int p0 = pt << 6;
#pragma unroll
    for (int i = 0; i < 8; ++i) {
      int c = i * 8 + r8;
      float v = base[(long long)c * 1024 + p0 + cl];
      t[c][cl] = (v - mu) * rs * gw[g * 64 + c] + gb[g * 64 + c];
    }
    __syncthreads();
#pragma unroll
    for (int i = 0; i < 8; ++i) {
      int pr = i * 8 + r8;
      h[(long long)(b * 1024 + p0 + pr) * 512 + g * 64 + cl] = f2b(t[cl][pr]);
    }
    __syncthreads();
  }
}

// ---------------- softmax in-place on S rows (bf16, 1024 per row) ----------------
__global__ __launch_bounds__(256)
void softmax_rows(unsigned short* __restrict__ S) {
  const long long row = (long long)blockIdx.x * 4 + (threadIdx.x >> 6);
  const int lane = threadIdx.x & 63;
  u16x8* p = (u16x8*)(S + row * 1024);
  u16x8 a = p[lane], b = p[64 + lane];
  float v[16];
#pragma unroll
  for (int i = 0; i < 8; ++i) { v[i] = b2f(a[i]); v[8 + i] = b2f(b[i]); }
  float m = v[0];
#pragma unroll
  for (int i = 1; i < 16; ++i) m = fmaxf(m, v[i]);
#pragma unroll
  for (int off = 32; off; off >>= 1) m = fmaxf(m, __shfl_xor(m, off));
  float s = 0.f;
#pragma unroll
  for (int i = 0; i < 16; ++i) { v[i] = __expf(v[i] - m); s += v[i]; }
#pragma unroll
  for (int off = 32; off; off >>= 1) s += __shfl_xor(s, off);
  float inv = 1.f / s;
#pragma unroll
  for (int i = 0; i < 8; ++i) { a[i] = f2b(v[i] * inv); b[i] = f2b(v[8 + i] * inv); }
  p[lane] = a;
  p[64 + lane] = b;
}

#define RSQRT_C 0.044194173824159216f
enum { EPI_BF16 = 0, EPI_QKV = 1, EPI_PROJ = 2 };

// ================= 256x256 8-wave 4-phase GEMM (B^T form), m201-style =================
// 8 waves 2Mx4N; per-wave 128x64 out = acc[8][4]. BK=64. LDS 128KB dynamic:
// buf[2] x units {A0,A1,B0,B1} (16KB each, rows x 128B, T2-swizzled k-blocks).
// Tile T phases (2 bars each): ph0 {stage u0,u1 of T+1; read A-low+B ks0; BAR; lgkm0;
// 16 MFMA; BAR}  ph1 {stage u2,u3; read A-high ks0; ...}  ph2 {read A-low+B ks1; ...}
// ph3 {read A-high ks1; vmcnt(0); ...}. Stage->conflicting-read separation >=1 barrier;
// vmcnt(0) drain is 2 barriers before the staged data is read.
template <int EPI>
__global__ __launch_bounds__(512, 1)
void gemm256(const unsigned short* __restrict__ A, int lda, long long sA,
             const unsigned short* __restrict__ B, int ldb, long long sB,
             void* __restrict__ Cv, int ldc, long long sC, int K,
             const float* __restrict__ bias, unsigned short* __restrict__ aux,
             int gx, int gy) {
  extern __shared__ char lds[];
  const int tid = threadIdx.x;
  const int wave = tid >> 6, lane = tid & 63;
  const int wr = wave >> 2, wc = wave & 3;

  const int nwg = gridDim.x;
  const int id0 = blockIdx.x;
  const int id = (id0 & 7) * (nwg >> 3) + (id0 >> 3);  // T1 (nwg % 8 == 0 everywhere)
  const int bn = id % gx;
  const int t1 = id / gx;
  const int bm = t1 % gy;
  const int bz = t1 / gy;

  const unsigned short* Ab = A + (long long)bz * sA + (long long)bm * 256 * lda;
  const unsigned short* Bb = B + (long long)bz * sB + (long long)bn * 256 * ldb;

  f32x4 acc[8][4] = {};
  const int frow = lane & 15;
  const int fkb = (lane >> 4) << 4;   // lane's 16B block within the 64B k-half
  const int swr = (frow & 7) << 4;    // T2 swizzle term (row&7, rows stride 16 within frag set)
  const int NT = K >> 6;

  // stage unit u (0:A-rows0..127 1:A-rows128..255 2:B-rows0..127 3:B-rows128..255)
  auto STAGE = [&](int kt, int u, int buf) {
    const unsigned short* Ob = (u < 2) ? Ab : Bb;
    const int ld = (u < 2) ? lda : ldb;
    const int half = u & 1;
    const int k0 = kt << 6;
#pragma unroll
    for (int i = 0; i < 2; ++i) {
      const int c = tid + (i << 9);             // chunk 0..1023 (16B each)
      const int r = c >> 3;                     // row 0..127 within unit
      const int sk = ((c & 7) ^ (r & 7)) << 3;  // pre-swizzled k offset (shorts)
      char* la = lds + buf * 65536 + u * 16384 + (((i << 9) + (wave << 6)) << 4);
      gload16(Ob + (long long)(half * 128 + r) * ld + k0 + sk, la);
    }
  };

  // prologue: tile 0 fully staged, drained, barrier before any reads
  STAGE(0, 0, 0); STAGE(0, 1, 0); STAGE(0, 2, 0); STAGE(0, 3, 0);
  asm volatile("s_waitcnt vmcnt(0)" ::: "memory");
  __builtin_amdgcn_s_barrier();

  for (int T = 0; T < NT; ++T) {
    const int cur = T & 1, nxt = cur ^ 1;
    const char* laA = lds + cur * 65536 + wr * 16384;
    const char* laB = lds + cur * 65536 + 32768 + (wc >> 1) * 16384;
    const int brow = (wc & 1) << 6;
    const bool pf = (T + 1 < NT);
    bf16x8 fA[4], fB[4];

    // -------- ph0: stage u0,u1(T+1); read A-low + B, ks=0; MFMA acc[0..3][*] --------
    if (pf) { STAGE(T + 1, 0, nxt); STAGE(T + 1, 1, nxt); }
#pragma unroll
    for (int f = 0; f < 4; ++f) {
      fA[f] = *(const bf16x8*)(laA + (f * 16 + frow) * 128 + (fkb ^ swr));
      fB[f] = *(const bf16x8*)(laB + (brow + f * 16 + frow) * 128 + (fkb ^ swr));
    }
    __builtin_amdgcn_s_barrier();
    asm volatile("s_waitcnt lgkmcnt(0)" ::: "memory");
    __builtin_amdgcn_sched_barrier(0);
    __builtin_amdgcn_s_setprio(1);
#pragma unroll
    for (int mi = 0; mi < 4; ++mi)
#pragma unroll
      for (int nj = 0; nj < 4; ++nj)
        acc[mi][nj] = __builtin_amdgcn_mfma_f32_16x16x32_bf16(fA[mi], fB[nj], acc[mi][nj], 0, 0, 0);
    __builtin_amdgcn_s_setprio(0);
    __builtin_amdgcn_s_barrier();

    // -------- ph1: stage u2,u3(T+1); read A-high ks=0; MFMA acc[4..7][*] --------
    if (pf) { STAGE(T + 1, 2, nxt); STAGE(T + 1, 3, nxt); }
#pragma unroll
    for (int f = 0; f < 4; ++f)
      fA[f] = *(const bf16x8*)(laA + ((f + 4) * 16 + frow) * 128 + (fkb ^ swr));
    __builtin_amdgcn_s_barrier();
    asm volatile("s_waitcnt lgkmcnt(0)" ::: "memory");
    __builtin_amdgcn_sched_barrier(0);
    __builtin_amdgcn_s_setprio(1);
#pragma unroll
    for (int mi = 0; mi < 4; ++mi)
#pragma unroll
      for (int nj = 0; nj < 4; ++nj)
        acc[mi + 4][nj] = __builtin_amdgcn_mfma_f32_16x16x32_bf16(fA[mi], fB[nj], acc[mi + 4][nj], 0, 0, 0);
    __builtin_amdgcn_s_setprio(0);
    __builtin_amdgcn_s_barrier();

    // -------- ph2: read A-low + B, ks=1; MFMA acc[0..3][*] --------
#pragma unroll
    for (int f = 0; f < 4; ++f) {
      fA[f] = *(const bf16x8*)(laA + (f * 16 + frow) * 128 + ((64 + fkb) ^ swr));
      fB[f] = *(const bf16x8*)(laB + (brow + f * 16 + frow) * 128 + ((64 + fkb) ^ swr));
    }
    __builtin_amdgcn_s_barrier();
    asm volatile("s_waitcnt lgkmcnt(0)" ::: "memory");
    __builtin_amdgcn_sched_barrier(0);
    __builtin_amdgcn_s_setprio(1);
#pragma unroll
    for (int mi = 0; mi < 4; ++mi)
#pragma unroll
      for (int nj = 0; nj < 4; ++nj)
        acc[mi][nj] = __builtin_amdgcn_mfma_f32_16x16x32_bf16(fA[mi], fB[nj], acc[mi][nj], 0, 0, 0);
    __builtin_amdgcn_s_setprio(0);
    __builtin_amdgcn_s_barrier();

    // -------- ph3: read A-high ks=1; vmcnt(0) (T+1 landed; 2 bars before its reads);
    //          MFMA acc[4..7][*] --------
#pragma unroll
    for (int f = 0; f < 4; ++f)
      fA[f] = *(const bf16x8*)(laA + ((f + 4) * 16 + frow) * 128 + ((64 + fkb) ^ swr));
    asm volatile("s_waitcnt vmcnt(0)" ::: "memory");
    __builtin_amdgcn_s_barrier();
    asm volatile("s_waitcnt lgkmcnt(0)" ::: "memory");
    __builtin_amdgcn_sched_barrier(0);
    __builtin_amdgcn_s_setprio(1);
#pragma unroll
    for (int mi = 0; mi < 4; ++mi)
#pragma unroll
      for (int nj = 0; nj < 4; ++nj)
        acc[mi + 4][nj] = __builtin_amdgcn_mfma_f32_16x16x32_bf16(fA[mi], fB[nj], acc[mi + 4][nj], 0, 0, 0);
    __builtin_amdgcn_s_setprio(0);
    __builtin_amdgcn_s_barrier();
  }

  // epilogue: frag row = (lane>>4)*4 + reg, col = lane&15 (verified mapping, R3-R7)
  const int rb = bm * 256 + wr * 128 + ((lane >> 4) << 2);
  const int cb = bn * 256 + wc * 64 + frow;
#pragma unroll
  for (int mi = 0; mi < 8; ++mi) {
#pragma unroll
    for (int nj = 0; nj < 4; ++nj) {
      const int col = cb + nj * 16;
      if constexpr (EPI == EPI_QKV) {
        if (col >= 1024) {  // V -> vt[b][col-1024][p] transposed, packed x4 along p
          const int row0 = rb + mi * 16;
          const int bb = row0 >> 10, p0 = row0 & 1023;
          u16x4 o;
#pragma unroll
          for (int r = 0; r < 4; ++r) o[r] = f2b(acc[mi][nj][r] + bias[col]);
          *(u16x4*)(aux + (long long)bb * 524288 + (long long)(col - 1024) * 1024 + p0) = o;
          continue;
        }
      }
#pragma unroll
      for (int r = 0; r < 4; ++r) {
        const int row = rb + mi * 16 + r;
        float v = acc[mi][nj][r];
        if constexpr (EPI == EPI_BF16) {
          ((unsigned short*)Cv)[(long long)bz * sC + (long long)row * ldc + col] = f2b(v);
        } else if constexpr (EPI == EPI_QKV) {
          v += bias[col];
          if (col < 512) v *= RSQRT_C;
          ((unsigned short*)Cv)[(long long)row * ldc + col] = f2b(v);
        }
      }
    }
  }
}

// ================= 128x128 2-phase GEMM (verified R4-R7) — PV & proj =================
DEVINL void stage_tile(const unsigned short* __restrict__ Ab,
                       const unsigned short* __restrict__ Bb,
                       int lda, int ldb, int k0, char* lb, int tid, int wave) {
#pragma unroll
  for (int i = 0; i < 4; ++i) {
    const int c = (i << 8) + tid;
    const int r = c >> 3;
    const int sk = ((c & 7) ^ (r & 7)) << 3;
    char* la = lb + (((i << 8) + (wave << 6)) << 4);
    gload16(Ab + (long long)r * lda + k0 + sk, la);
    gload16(Bb + (long long)r * ldb + k0 + sk, la + 16384);
  }
}

template <int EPI>
__global__ __launch_bounds__(256, 2)
void gemm_bt(const unsigned short* __restrict__ A, int lda, long long sA,
             const unsigned short* __restrict__ B, int ldb, long long sB,
             void* __restrict__ Cv, int ldc, long long sC, int K,
             const float* __restrict__ bias, const float* __restrict__ resid,
             int gx, int gy) {
  __shared__ char lds[65536];
  const int tid = threadIdx.x;
  const int wave = tid >> 6, lane = tid & 63;
  const int wr = wave >> 1, wc = wave & 1;

  const int nwg = gridDim.x;
  const int id0 = blockIdx.x;
  const int id = (id0 & 7) * (nwg >> 3) + (id0 >> 3);
  const int bn = id % gx;
  const int t1 = id / gx;
  const int bm = t1 % gy;
  const int bz = t1 / gy;

  const unsigned short* Ab = A + (long long)bz * sA + (long long)bm * 128 * lda;
  const unsigned short* Bb = B + (long long)bz * sB + (long long)bn * 128 * ldb;

  f32x4 acc[4][4] = {};
  const int frow = lane & 15;
  const int fkb = (lane >> 4) << 4;
  const int swr = (frow & 7) << 4;
  const int NT = K >> 6;

  stage_tile(Ab, Bb, lda, ldb, 0, lds, tid, wave);
  stage_tile(Ab, Bb, lda, ldb, 64, lds + 32768, tid, wave);
  asm volatile("s_waitcnt vmcnt(8)" ::: "memory");

  for (int kt = 0; kt < NT; ++kt) {
    const int cur = kt & 1;
    __builtin_amdgcn_s_barrier();
    asm volatile("" ::: "memory");
    const char* lb = lds + cur * 32768;
    __builtin_amdgcn_s_setprio(1);
#pragma unroll
    for (int ks = 0; ks < 2; ++ks) {
      bf16x8 af[4], bfr[4];
      const int kb = (ks << 6) + fkb;
#pragma unroll
      for (int f = 0; f < 4; ++f) {
        const int ar = (wr << 6) + (f << 4) + frow;
        af[f] = *reinterpret_cast<const bf16x8*>(lb + ar * 128 + (kb ^ swr));
        const int br = (wc << 6) + (f << 4) + frow;
        bfr[f] = *reinterpret_cast<const bf16x8*>(lb + 16384 + br * 128 + (kb ^ swr));
      }
#pragma unroll
      for (int i = 0; i < 4; ++i)
#pragma unroll
        for (int j = 0; j < 4; ++j)
          acc[i][j] = __builtin_amdgcn_mfma_f32_16x16x32_bf16(af[i], bfr[j], acc[i][j], 0, 0, 0);
    }
    __builtin_amdgcn_s_setprio(0);
    asm volatile("" ::: "memory");
    __builtin_amdgcn_s_barrier();
    if (kt + 2 < NT) {
      stage_tile(Ab, Bb, lda, ldb, (kt + 2) << 6, lds + cur * 32768, tid, wave);
      asm volatile("s_waitcnt vmcnt(8)" ::: "memory");
    } else if (kt + 2 == NT) {
      asm volatile("s_waitcnt vmcnt(0)" ::: "memory");
    }
  }

  const int rb = bm * 128 + (wr << 6) + ((lane >> 4) << 2);
  const int cb = bn * 128 + (wc << 6) + frow;
#pragma unroll
  for (int i = 0; i < 4; ++i) {
#pragma unroll
    for (int j = 0; j < 4; ++j) {
      const int col = cb + (j << 4);
#pragma unroll
      for (int r = 0; r < 4; ++r) {
        const int row = rb + (i << 4) + r;
        float v = acc[i][j][r];
        if constexpr (EPI == EPI_BF16) {
          ((unsigned short*)Cv)[(long long)bz * sC + (long long)row * ldc + col] = f2b(v);
        } else {  // EPI_PROJ: fp32 out + per-row bias + residual
          long long idx = (long long)bz * sC + (long long)row * ldc + col;
          ((float*)Cv)[idx] = v + bias[row] + resid[idx];
        }
      }
    }
  }
}

// ---------------- launch ----------------
extern "C" void kernel_launch(void* const* d_in, const int* in_sizes, int n_in,
                              void* d_out, int out_size, void* d_ws, size_t ws_size,
                              hipStream_t stream) {
  const float* x      = (const float*)d_in[0];
  const float* gn_w   = (const float*)d_in[1];
  const float* gn_b   = (const float*)d_in[2];
  const float* qkv_w  = (const float*)d_in[3];
  const float* qkv_b  = (const float*)d_in[4];
  const float* proj_w = (const float*)d_in[5];
  const float* proj_b = (const float*)d_in[6];

  char* ws = (char*)d_ws;
  unsigned short* wq   = (unsigned short*)(ws + 1024);      // 1536x512 bf16
  unsigned short* wp   = (unsigned short*)(ws + 1573888);   // 512x512 bf16
  unsigned short* h    = (unsigned short*)(ws + 2098176);   // (B,N,C) bf16 16.8MB
  unsigned short* qkv  = (unsigned short*)(ws + 18875392);  // (B,N,2C) q,k ld1024 33.6MB
  unsigned short* vt   = (unsigned short*)(ws + 52429824);  // (B,C,N) bf16 16.8MB
  unsigned short* O    = h;                                 // h dead after QKV gemm
  unsigned short* S    = (unsigned short*)d_out;            // (B,N,N) bf16

  // allow 128KB dynamic LDS for the 256^2 kernels (host-side attribute; idempotent)
  (void)hipFuncSetAttribute(reinterpret_cast<const void*>(&gemm256<EPI_QKV>),
                            hipFuncAttributeMaxDynamicSharedMemorySize, 131072);
  (void)hipFuncSetAttribute(reinterpret_cast<const void*>(&gemm256<EPI_BF16>),
                            hipFuncAttributeMaxDynamicSharedMemorySize, 131072);

  f2bf_all<<<1024, 256, 0, stream>>>(qkv_w, proj_w, wq, wp);
  gn_fused<<<128, 512, 0, stream>>>(x, gn_w, gn_b, h);
  // QKV: (16384x512)x(1536x512)^T; 256^2 grid 6x64 = 384
  gemm256<EPI_QKV><<<384, 512, 131072, stream>>>(
      h, 512, 0, wq, 512, 0, qkv, 1024, 0, 512, qkv_b, vt, 6, 64);
  // S = q k^T per batch: 256^2 grid 4x4x16 = 256
  gemm256<EPI_BF16><<<256, 512, 131072, stream>>>(
      qkv, 1024, 1024LL * 1024, qkv + 512, 1024, 1024LL * 1024,
      S, 1024, 1024LL * 1024, 512, nullptr, nullptr, 4, 4);
  softmax_rows<<<4096, 256, 0, stream>>>(S);
  // O = P V: 128^2 grid 4x8x16 = 512
  gemm_bt<EPI_BF16><<<512, 256, 0, stream>>>(
      S, 1024, 1024LL * 1024, vt, 1024, 512LL * 1024,
      O, 512, 1024LL * 512, 1024, nullptr, nullptr, 4, 8);
  // proj (out^T form): 128^2 grid 8x4x16 = 512
  gemm_bt<EPI_PROJ><<<512, 256, 0, stream>>>(
      wp, 512, 0, O, 512, 1024LL * 512,
      d_out, 1024, 512LL * 1024, 512, proj_b, x, 8, 4);
}